// Round 1
// baseline (729.750 us; speedup 1.0000x reference)
//
#include <hip/hip_runtime.h>
#include <hip/hip_bf16.h>

#define H 128
#define H1 129
#define NSLAB (H1 * H1)          // 16641 slabs of 129 W1-rows each
#define KP 164                   // LDS k-pitch (bf16 elems): mult of 4, not mult of 16 -> aligned b64, conflict-free reads
#define NBLK 1024                // 4 blocks / CU

typedef __attribute__((ext_vector_type(8))) short short8;
typedef __attribute__((ext_vector_type(4))) float float4v;
typedef __attribute__((ext_vector_type(2))) int int2v;
typedef __attribute__((ext_vector_type(4))) int int4v;

__device__ __forceinline__ unsigned short f2bf_bits(float x) {
    return __builtin_bit_cast(unsigned short, __float2bfloat16(x));
}
__device__ __forceinline__ unsigned packbf(float x, float y) {
    return (unsigned)f2bf_bits(x) | ((unsigned)f2bf_bits(y) << 16);
}

// Stage 1: y1_raw[b,h] = sum_{ij,k} a_h[b,i] v_h[b,j] t_h[b,k] W1[ij*129+k, h]
// Per slab ij: D = t_h @ W1slab via MFMA (t_h bf16 in regs), then y1acc += av * D.
__global__ __launch_bounds__(256, 4) void k1_partial(
        const float* __restrict__ v, const float* __restrict__ a,
        const float* __restrict__ t, const float* __restrict__ W1,
        float* __restrict__ acc)
{
    __shared__ short lds[64 * KP];   // transposed slab: [h][k] bf16

    const int tid  = threadIdx.x;
    const int wv   = tid >> 6;       // wave 0..3 -> owns batch rows [16wv,16wv+16)
    const int lane = tid & 63;
    const int quad = lane >> 4;
    const int l15  = lane & 15;

    // zero-fill pad region k in [130, KP) once (staging writes only k<130)
    for (int idx = tid; idx < 64 * (KP - 130); idx += 256) {
        int n = idx / (KP - 130), k = 130 + idx % (KP - 130);
        lds[n * KP + k] = 0;
    }

    // t_h fragments (A operand), bf16, padded with zeros for k>=129.
    // A[m][k]: m = lane&15 -> batch row, k = 32*s + 8*quad + j
    short8 tf[5];
    const int bt = 16 * wv + l15;
    #pragma unroll
    for (int s = 0; s < 5; ++s) {
        #pragma unroll
        for (int j = 0; j < 8; ++j) {
            int k = 32 * s + 8 * quad + j;
            float val = (k == 0) ? 1.0f : ((k <= H) ? t[bt * H + k - 1] : 0.0f);
            tf[s][j] = (short)f2bf_bits(val);
        }
    }

    const float4v vz = {0.f, 0.f, 0.f, 0.f};
    float4v y1acc[4] = {vz, vz, vz, vz};

    const int s0 = (int)(((long long)blockIdx.x * NSLAB) / NBLK);
    const int s1 = (int)(((long long)(blockIdx.x + 1) * NSLAB) / NBLK);
    int si = s0 / H1, sj = s0 % H1;

    // staging decomposition: lanes -> quad q = tid&15 (coalesced rows), pair p16 = tid>>4
    const int q = tid & 15;
    const int p16 = tid >> 4;

    for (int sl = s0; sl < s1; ++sl) {
        const float* Wb = W1 + (long long)sl * (H1 * 64);

        // ---- stage slab -> LDS (transposed, fp32->bf16) ----
        float4v ra[4], rb[4];
        #pragma unroll
        for (int it = 0; it < 4; ++it) {
            int p = it * 16 + p16;                 // row pair 0..63 -> rows 2p, 2p+1
            ra[it] = *reinterpret_cast<const float4v*>(Wb + (2 * p) * 64 + q * 4);
            rb[it] = *reinterpret_cast<const float4v*>(Wb + (2 * p + 1) * 64 + q * 4);
        }
        float lastrow = 0.f;
        if (tid < 64) lastrow = Wb[128 * 64 + tid];

        #pragma unroll
        for (int it = 0; it < 4; ++it) {
            int p = it * 16 + p16;
            #pragma unroll
            for (int c = 0; c < 4; ++c) {
                int n = q * 4 + c;
                *reinterpret_cast<unsigned*>(&lds[n * KP + 2 * p]) = packbf(ra[it][c], rb[it][c]);
            }
        }
        if (tid < 64) {
            *reinterpret_cast<unsigned*>(&lds[tid * KP + 128]) = packbf(lastrow, 0.f);
        }
        __syncthreads();

        // ---- av scalars (fp32, exact) ----
        float4v avv;
        #pragma unroll
        for (int r = 0; r < 4; ++r) {
            int br = 16 * wv + quad * 4 + r;       // C/D row for reg r
            float ah = (si == 0) ? 1.0f : a[br * H + si - 1];
            float vh = (sj == 0) ? 1.0f : v[br * H + sj - 1];
            avv[r] = ah * vh;
        }

        // ---- MFMA: D = t_h @ W1slab ----
        float4v D[4] = {vz, vz, vz, vz};
        #pragma unroll
        for (int s = 0; s < 5; ++s) {
            #pragma unroll
            for (int nt = 0; nt < 4; ++nt) {
                int n = nt * 16 + l15;
                int sa = n * KP + 32 * s + 8 * quad;
                int2v lo = *reinterpret_cast<const int2v*>(&lds[sa]);
                int2v hi = *reinterpret_cast<const int2v*>(&lds[sa + 4]);
                int4v w; w.x = lo.x; w.y = lo.y; w.z = hi.x; w.w = hi.y;
                short8 bf = __builtin_bit_cast(short8, w);
                D[nt] = __builtin_amdgcn_mfma_f32_16x16x32_bf16(tf[s], bf, D[nt], 0, 0, 0);
            }
        }
        #pragma unroll
        for (int nt = 0; nt < 4; ++nt) y1acc[nt] += avv * D[nt];

        __syncthreads();

        ++sj; if (sj == H1) { sj = 0; ++si; }
    }

    // ---- reduce across blocks ----
    #pragma unroll
    for (int nt = 0; nt < 4; ++nt) {
        int h = nt * 16 + l15;
        #pragma unroll
        for (int r = 0; r < 4; ++r) {
            int br = 16 * wv + quad * 4 + r;
            unsafeAtomicAdd(&acc[br * 64 + h], y1acc[nt][r]);
        }
    }
}

// Stage 2: bias+relu, layer2, layer3 (tiny: 64x64 -> 64x32 -> 64)
__global__ void k2_tail(const float* __restrict__ acc, const float* __restrict__ b1,
                        const float* __restrict__ W2, const float* __restrict__ b2,
                        const float* __restrict__ W3, const float* __restrict__ b3,
                        float* __restrict__ out)
{
    __shared__ float y1s[64 * 64];
    __shared__ float y2s[64 * 32];
    const int tid = threadIdx.x;

    for (int e = tid; e < 64 * 64; e += 256) {
        float x = acc[e] + b1[e & 63];
        y1s[e] = x > 0.f ? x : 0.f;
    }
    __syncthreads();
    for (int e = tid; e < 64 * 32; e += 256) {
        int b = e >> 5, h2 = e & 31;
        float s = b2[h2];
        #pragma unroll 8
        for (int h = 0; h < 64; ++h) s += y1s[b * 64 + h] * W2[h * 32 + h2];
        y2s[e] = s > 0.f ? s : 0.f;
    }
    __syncthreads();
    if (tid < 64) {
        float s = b3[0];
        #pragma unroll
        for (int h2 = 0; h2 < 32; ++h2) s += y2s[tid * 32 + h2] * W3[h2];
        out[tid] = s;
    }
}

extern "C" void kernel_launch(void* const* d_in, const int* in_sizes, int n_in,
                              void* d_out, int out_size, void* d_ws, size_t ws_size,
                              hipStream_t stream) {
    const float* v  = (const float*)d_in[0];
    const float* a  = (const float*)d_in[1];
    const float* t  = (const float*)d_in[2];
    const float* W1 = (const float*)d_in[3];
    const float* b1 = (const float*)d_in[4];
    const float* W2 = (const float*)d_in[5];
    const float* b2 = (const float*)d_in[6];
    const float* W3 = (const float*)d_in[7];
    const float* b3 = (const float*)d_in[8];
    float* acc = (float*)d_ws;

    hipMemsetAsync(acc, 0, 64 * 64 * sizeof(float), stream);
    hipLaunchKernelGGL(k1_partial, dim3(NBLK), dim3(256), 0, stream, v, a, t, W1, acc);
    hipLaunchKernelGGL(k2_tail, dim3(1), dim3(256), 0, stream,
                       acc, b1, W2, b2, W3, b3, (float*)d_out);
}